// Round 12
// baseline (742.140 us; speedup 1.0000x reference)
//
#include <hip/hip_runtime.h>

// Problem constants (from reference)
#define R_     4096
#define C_     16384
#define B_     32
#define NB_    (C_ / B_)     // 512
#define NC_    16
#define TOTAL  (R_ * C_)     // 67108864
#define NBLK   (TOTAL / B_)  // 2097152 scale blocks
#define TBITS  17
#define TSIZE  (1 << TBITS)  // 131072 hash slots (load factor 0.5)
#define TWORDS (TSIZE * 2)   // 262144 ints = 1 MB (keys + vals)

#define GRID_  2048
#define BLK_   256
#define NV_    (GRID_ * BLK_)                  // 524288 threads
#define SB_    (NBLK / NV_)                    // 4 superblocks/thread
static_assert(SB_ * NV_ == NBLK, "blocks tile exactly");
static_assert(NV_ >= TWORDS, "one store per thread covers table init");

typedef float f32x4 __attribute__((ext_vector_type(4)));

// Force a wave-uniform float into an SGPR (keeps c[16]+bnd[15] out of VGPRs).
__device__ __forceinline__ float rfl(float x) {
    return __int_as_float(__builtin_amdgcn_readfirstlane(__float_as_int(x)));
}

// ---------------------------------------------------------------------------
// Main dequant kernel.
//   w = centroids[searchsorted(boundaries, x)] * s,  ties DOWN (side='left')
//   x = fl32( e * fl32(1/s) )   <- matches XLA's div->mul(1/s) rewrite
// VERIFIED BITWISE (round 5, absmax 0.0). Frozen numerics:
//  - r = fl32(1/s): plain f32 IEEE divide (fast-math proven OFF in R1/R3)
//  - boundaries (c[j+1]+c[j])*0.5f ; strict '>' chain; final w*s single mul.
//
// Memory config (A/B-established): PLAIN loads (R9), NT stores (R9 131 vs
// R10 plain 148), stores grouped tightly (R11: interleaving loads between
// store groups broke write-combining, WRITE 269->391 MB, 163 µs).
//
// R12: BLOCK-SEQUENTIAL mapping. Thread owns one 32-elem scale block
// (8 consecutive float4s = one 128B line per lane) x 4 superblocks:
//  - wave footprint per burst: contiguous 8 KB (DRAM row locality)
//  - 7/8 of loads are L1 hits (lane's line fetched at k=0)
//  - 1 scale load + 1 f32 divide per 8 float4s (was per 1)
//  - i4>>3 == blk exactly: 8t..8t+7 >> 3 == t (no block crossing)
// ---------------------------------------------------------------------------
__global__ __launch_bounds__(BLK_, 8) void dequant_kernel(
    const float* __restrict__ master,
    const float* __restrict__ centroids,
    const float* __restrict__ scale,
    float* __restrict__ out,
    int* __restrict__ table)
{
    // Fold the 1 MB hash-table init into this kernel (one store for the
    // first TWORDS threads) — removes a separate fill dispatch.
    const int tid = blockIdx.x * BLK_ + threadIdx.x;
    if (tid < TWORDS) __builtin_nontemporal_store(-1, table + tid);

    float c[NC_];
    float bnd[NC_ - 1];
#pragma unroll
    for (int j = 0; j < NC_; ++j) c[j] = rfl(centroids[j]);
#pragma unroll
    for (int j = 0; j < NC_ - 1; ++j)
        bnd[j] = rfl((c[j + 1] + c[j]) * 0.5f);  // f32 add, *0.5 exact; SGPR

    const f32x4* m4 = reinterpret_cast<const f32x4*>(master);
    f32x4*       o4 = reinterpret_cast<f32x4*>(out);

#pragma unroll
    for (int sb = 0; sb < SB_; ++sb) {
        const int blk   = tid + sb * NV_;     // scale block index
        const int base4 = blk * 8;            // first float4 of the block

        const float s = scale[blk];           // one scale load per block
        const float r = 1.0f / s;             // one correctly-rounded recip

        f32x4 v[8];
#pragma unroll
        for (int k = 0; k < 8; ++k)
            v[k] = m4[base4 + k];             // k=0 fetches the lane's 128B
                                              // line; k=1..7 are L1 hits
        f32x4 q[8];
#pragma unroll
        for (int k = 0; k < 8; ++k) {
#pragma unroll
            for (int kk = 0; kk < 4; ++kk) {
                float x = (s != 0.0f) ? (v[k][kk] * r) : 0.0f;  // safe_div
                // idx = #{bnd[j] < x}: ties DOWN (searchsorted side='left')
                float w = c[0];
#pragma unroll
                for (int j = 0; j < NC_ - 1; ++j)
                    w = (x > bnd[j]) ? c[j + 1] : w;
                q[k][kk] = w * s;
            }
        }
        // Stores grouped tightly back-to-back (R11 lesson: WC-friendly)
#pragma unroll
        for (int k = 0; k < 8; ++k)
            __builtin_nontemporal_store(q[k], o4 + base4 + k);
    }
}

// ---------------------------------------------------------------------------
// Sparse override with numpy last-write-wins semantics for duplicate indices.
// Hash table (init by dequant_kernel): keys[TSIZE]=-1, vals[TSIZE]=-1.
// Pass 1: insert key, atomicMax source-index. Pass 2: winner writes.
// ---------------------------------------------------------------------------
__global__ void hash_insert(const int* __restrict__ sidx, int ns,
                            int* __restrict__ keys, int* __restrict__ vals)
{
    int i = blockIdx.x * blockDim.x + threadIdx.x;
    if (i >= ns) return;
    int key = sidx[i];
    unsigned h = ((unsigned)key * 2654435761u) >> (32 - TBITS);
    for (;;) {
        int prev = atomicCAS(&keys[h], -1, key);
        if (prev == -1 || prev == key) {
            atomicMax(&vals[h], i);   // last occurrence (max i) wins
            return;
        }
        h = (h + 1) & (TSIZE - 1);
    }
}

__global__ void hash_scatter(const int* __restrict__ sidx,
                             const float* __restrict__ sw, int ns,
                             const int* __restrict__ keys,
                             const int* __restrict__ vals,
                             float* __restrict__ out)
{
    int i = blockIdx.x * blockDim.x + threadIdx.x;
    if (i >= ns) return;
    int key = sidx[i];
    unsigned h = ((unsigned)key * 2654435761u) >> (32 - TBITS);
    for (;;) {
        if (keys[h] == key) {
            if (vals[h] == i) out[key] = sw[i];
            return;
        }
        h = (h + 1) & (TSIZE - 1);
    }
}

// Fallback if workspace is unexpectedly tiny: sequential = last-write-wins.
__global__ void serial_scatter(const int* __restrict__ sidx,
                               const float* __restrict__ sw, int ns,
                               float* __restrict__ out)
{
    if (blockIdx.x == 0 && threadIdx.x == 0) {
        for (int i = 0; i < ns; ++i) out[sidx[i]] = sw[i];
    }
}

extern "C" void kernel_launch(void* const* d_in, const int* in_sizes, int n_in,
                              void* d_out, int out_size, void* d_ws, size_t ws_size,
                              hipStream_t stream)
{
    const float* master    = (const float*)d_in[0];
    const float* centroids = (const float*)d_in[1];
    const float* scale     = (const float*)d_in[2];
    const float* sweight   = (const float*)d_in[3];
    const int*   sidx      = (const int*)d_in[4];
    float*       out       = (float*)d_out;
    const int    ns        = in_sizes[4];

    const size_t table_bytes = (size_t)TWORDS * sizeof(int);
    if (ws_size >= table_bytes) {
        int* keys = (int*)d_ws;
        int* vals = keys + TSIZE;
        // dequant also initializes the hash table (saves a fill dispatch)
        dequant_kernel<<<GRID_, BLK_, 0, stream>>>(master, centroids, scale,
                                                   out, keys);
        int blocks = (ns + 255) / 256;
        hash_insert<<<blocks, 256, 0, stream>>>(sidx, ns, keys, vals);
        hash_scatter<<<blocks, 256, 0, stream>>>(sidx, sweight, ns, keys, vals, out);
    } else {
        dequant_kernel<<<GRID_, BLK_, 0, stream>>>(master, centroids, scale,
                                                   out, (int*)d_ws);
        serial_scatter<<<1, 1, 0, stream>>>(sidx, sweight, ns, out);
    }
}

// Round 13
// 128.526 us; speedup vs baseline: 5.7742x; 5.7742x over previous
//
#include <hip/hip_runtime.h>

// Problem constants (from reference)
#define R_     4096
#define C_     16384
#define B_     32
#define NB_    (C_ / B_)     // 512
#define NC_    16
#define TOTAL  (R_ * C_)     // 67108864
#define TBITS  17
#define TSIZE  (1 << TBITS)  // 131072 hash slots (load factor 0.5)
#define TWORDS (TSIZE * 2)   // 262144 ints = 1 MB (keys + vals)

#define GRID_  4096
#define BLK_   256
#define NV_    (GRID_ * BLK_)                  // 1048576 threads
#define ITERS_ (TOTAL / 4 / NV_)               // 16 float4 per thread
#define UN_    2                               // batch depth (R9 champion)
static_assert(NV_ * ITERS_ * 4 == TOTAL, "grid must tile exactly");
static_assert(ITERS_ % UN_ == 0, "unroll divides iters");
static_assert(NV_ >= TWORDS, "one store per thread covers table init");

typedef float f32x4 __attribute__((ext_vector_type(4)));

// Force a wave-uniform float into an SGPR (keeps c[16]+bnd[15] out of VGPRs).
__device__ __forceinline__ float rfl(float x) {
    return __int_as_float(__builtin_amdgcn_readfirstlane(__float_as_int(x)));
}

// ---------------------------------------------------------------------------
// Main dequant kernel — R9 champion structure (130.9 µs), grid 4096.
//   w = centroids[searchsorted(boundaries, x)] * s,  ties DOWN (side='left')
//   x = fl32( e * fl32(1/s) )   <- matches XLA's div->mul(1/s) rewrite
// VERIFIED BITWISE (round 5, absmax 0.0). Frozen numerics:
//  - r = fl32(1/s): plain f32 IEEE divide (fast-math proven OFF in R1/R3)
//  - boundaries (c[j+1]+c[j])*0.5f ; strict '>' chain; final w*s single mul.
//
// A/B ledger (total µs): lane-interleaved simple {plain loads, NT stores}
//   = 130.9 (R9)  <  nt-loads 132.4 (R8)  <  nt+nt 133.6 (R6)
//   <  plain-stores 148 (R10, L3 thrash: FETCH 138->276 MB)
//   <  sw-pipeline 163 (R11, WC broken: WRITE 269->391 MB)
//   <  per-lane-contiguous 742 (R12, uncoalesced: stride-128B across lanes)
// R13: grid 2048->4096 (ITERS 32->16) for CU load-balance / shorter drain
// (R9 OccupancyPercent ~70% with no occupancy limiter => imbalance).
// ---------------------------------------------------------------------------
__global__ __launch_bounds__(BLK_, 8) void dequant_kernel(
    const float* __restrict__ master,
    const float* __restrict__ centroids,
    const float* __restrict__ scale,
    float* __restrict__ out,
    int* __restrict__ table)
{
    // Fold the 1 MB hash-table init into this kernel (one store for the
    // first TWORDS threads) — removes a separate fill dispatch.
    const int tid = blockIdx.x * BLK_ + threadIdx.x;
    if (tid < TWORDS) __builtin_nontemporal_store(-1, table + tid);

    float c[NC_];
    float bnd[NC_ - 1];
#pragma unroll
    for (int j = 0; j < NC_; ++j) c[j] = rfl(centroids[j]);
#pragma unroll
    for (int j = 0; j < NC_ - 1; ++j)
        bnd[j] = rfl((c[j + 1] + c[j]) * 0.5f);  // f32 add, *0.5 exact; SGPR

    const f32x4* m4 = reinterpret_cast<const f32x4*>(master);
    f32x4*       o4 = reinterpret_cast<f32x4*>(out);

    for (int k0 = 0; k0 < ITERS_; k0 += UN_) {
        f32x4 v[UN_];
        float s[UN_];
        float r[UN_];

#pragma unroll
        for (int u = 0; u < UN_; ++u) {
            const int i4 = tid + (k0 + u) * NV_;
            v[u] = m4[i4];                 // plain cached load (R9 A/B)
            s[u] = scale[i4 >> 3];
        }
#pragma unroll
        for (int u = 0; u < UN_; ++u)
            r[u] = 1.0f / s[u];            // correctly-rounded f32 reciprocal

#pragma unroll
        for (int u = 0; u < UN_; ++u) {
            f32x4 q;
#pragma unroll
            for (int kk = 0; kk < 4; ++kk) {
                float x = (s[u] != 0.0f) ? (v[u][kk] * r[u]) : 0.0f;  // safe_div
                // idx = #{bnd[j] < x}: ties DOWN (searchsorted side='left')
                float w = c[0];
#pragma unroll
                for (int j = 0; j < NC_ - 1; ++j)
                    w = (x > bnd[j]) ? c[j + 1] : w;
                q[kk] = w * s[u];
            }
            const int i4 = tid + (k0 + u) * NV_;
            __builtin_nontemporal_store(q, o4 + i4);   // NT store (R9/R10 A/B)
        }
    }
}

// ---------------------------------------------------------------------------
// Sparse override with numpy last-write-wins semantics for duplicate indices.
// Hash table (init by dequant_kernel): keys[TSIZE]=-1, vals[TSIZE]=-1.
// Pass 1: insert key, atomicMax source-index. Pass 2: winner writes.
// ---------------------------------------------------------------------------
__global__ void hash_insert(const int* __restrict__ sidx, int ns,
                            int* __restrict__ keys, int* __restrict__ vals)
{
    int i = blockIdx.x * blockDim.x + threadIdx.x;
    if (i >= ns) return;
    int key = sidx[i];
    unsigned h = ((unsigned)key * 2654435761u) >> (32 - TBITS);
    for (;;) {
        int prev = atomicCAS(&keys[h], -1, key);
        if (prev == -1 || prev == key) {
            atomicMax(&vals[h], i);   // last occurrence (max i) wins
            return;
        }
        h = (h + 1) & (TSIZE - 1);
    }
}

__global__ void hash_scatter(const int* __restrict__ sidx,
                             const float* __restrict__ sw, int ns,
                             const int* __restrict__ keys,
                             const int* __restrict__ vals,
                             float* __restrict__ out)
{
    int i = blockIdx.x * blockDim.x + threadIdx.x;
    if (i >= ns) return;
    int key = sidx[i];
    unsigned h = ((unsigned)key * 2654435761u) >> (32 - TBITS);
    for (;;) {
        if (keys[h] == key) {
            if (vals[h] == i) out[key] = sw[i];
            return;
        }
        h = (h + 1) & (TSIZE - 1);
    }
}

// Fallback if workspace is unexpectedly tiny: sequential = last-write-wins.
__global__ void serial_scatter(const int* __restrict__ sidx,
                               const float* __restrict__ sw, int ns,
                               float* __restrict__ out)
{
    if (blockIdx.x == 0 && threadIdx.x == 0) {
        for (int i = 0; i < ns; ++i) out[sidx[i]] = sw[i];
    }
}

extern "C" void kernel_launch(void* const* d_in, const int* in_sizes, int n_in,
                              void* d_out, int out_size, void* d_ws, size_t ws_size,
                              hipStream_t stream)
{
    const float* master    = (const float*)d_in[0];
    const float* centroids = (const float*)d_in[1];
    const float* scale     = (const float*)d_in[2];
    const float* sweight   = (const float*)d_in[3];
    const int*   sidx      = (const int*)d_in[4];
    float*       out       = (float*)d_out;
    const int    ns        = in_sizes[4];

    const size_t table_bytes = (size_t)TWORDS * sizeof(int);
    if (ws_size >= table_bytes) {
        int* keys = (int*)d_ws;
        int* vals = keys + TSIZE;
        // dequant also initializes the hash table (saves a fill dispatch)
        dequant_kernel<<<GRID_, BLK_, 0, stream>>>(master, centroids, scale,
                                                   out, keys);
        int blocks = (ns + 255) / 256;
        hash_insert<<<blocks, 256, 0, stream>>>(sidx, ns, keys, vals);
        hash_scatter<<<blocks, 256, 0, stream>>>(sidx, sweight, ns, keys, vals, out);
    } else {
        dequant_kernel<<<GRID_, BLK_, 0, stream>>>(master, centroids, scale,
                                                   out, (int*)d_ws);
        serial_scatter<<<1, 1, 0, stream>>>(sidx, sweight, ns, out);
    }
}

// Round 14
// 122.941 us; speedup vs baseline: 6.0366x; 1.0454x over previous
//
#include <hip/hip_runtime.h>

// Problem constants (from reference)
#define R_     4096
#define C_     16384
#define B_     32
#define NB_    (C_ / B_)     // 512
#define NC_    16
#define TOTAL  (R_ * C_)     // 67108864
#define TBITS  17
#define TSIZE  (1 << TBITS)  // 131072 hash slots (load factor 0.5)
#define TWORDS (TSIZE * 2)   // 262144 ints = 1 MB (keys + vals)

#define GRID_  8192
#define BLK_   256
#define NV_    (GRID_ * BLK_)                  // 2097152 threads
#define ITERS_ (TOTAL / 4 / NV_)               // 8 float4 per thread
#define UN_    2                               // batch depth (R9 champion)
static_assert(NV_ * ITERS_ * 4 == TOTAL, "grid must tile exactly");
static_assert(ITERS_ % UN_ == 0, "unroll divides iters");
static_assert(NV_ >= TWORDS, "one store per thread covers table init");

typedef float f32x4 __attribute__((ext_vector_type(4)));

// Force a wave-uniform float into an SGPR (keeps c[16]+bnd[15] out of VGPRs).
__device__ __forceinline__ float rfl(float x) {
    return __int_as_float(__builtin_amdgcn_readfirstlane(__float_as_int(x)));
}

// ---------------------------------------------------------------------------
// Main dequant kernel — R9 champion structure.
//   w = centroids[searchsorted(boundaries, x)] * s,  ties DOWN (side='left')
//   x = fl32( e * fl32(1/s) )   <- matches XLA's div->mul(1/s) rewrite
// VERIFIED BITWISE (round 5, absmax 0.0). Frozen numerics:
//  - r = fl32(1/s): plain f32 IEEE divide (fast-math proven OFF in R1/R3)
//  - boundaries (c[j+1]+c[j])*0.5f ; strict '>' chain; final w*s single mul.
//
// A/B ledger (total µs): lane-interleaved simple {plain loads, NT stores}
//   = 130.9 (R9) / 128.5 (R13, grid 4096)  <  nt-loads 132.4 (R8)
//   <  nt+nt 133.6 (R6)  <  plain-stores 148 (R10, L3 thrash)
//   <  sw-pipeline 163 (R11, WC broken)  <  per-lane-contig 742 (R12).
// R14 micro-tweaks: (a) scale loads issued BEFORE vector loads so the f32-div
// overlaps master-load latency (in-order vmcnt: waiting on s no longer waits
// on v); (b) grid 8192 (ITERS 8) for drain balance.
// ---------------------------------------------------------------------------
__global__ __launch_bounds__(BLK_, 8) void dequant_kernel(
    const float* __restrict__ master,
    const float* __restrict__ centroids,
    const float* __restrict__ scale,
    float* __restrict__ out,
    int* __restrict__ table)
{
    // Fold the 1 MB hash-table init into this kernel (one store for the
    // first TWORDS threads) — removes a separate fill dispatch.
    const int tid = blockIdx.x * BLK_ + threadIdx.x;
    if (tid < TWORDS) __builtin_nontemporal_store(-1, table + tid);

    float c[NC_];
    float bnd[NC_ - 1];
#pragma unroll
    for (int j = 0; j < NC_; ++j) c[j] = rfl(centroids[j]);
#pragma unroll
    for (int j = 0; j < NC_ - 1; ++j)
        bnd[j] = rfl((c[j + 1] + c[j]) * 0.5f);  // f32 add, *0.5 exact; SGPR

    const f32x4* m4 = reinterpret_cast<const f32x4*>(master);
    f32x4*       o4 = reinterpret_cast<f32x4*>(out);

    for (int k0 = 0; k0 < ITERS_; k0 += UN_) {
        f32x4 v[UN_];
        float s[UN_];
        float r[UN_];

        // Scale loads FIRST: r=1/s depends only on s; div overlaps v-latency.
#pragma unroll
        for (int u = 0; u < UN_; ++u)
            s[u] = scale[(tid + (k0 + u) * NV_) >> 3];
#pragma unroll
        for (int u = 0; u < UN_; ++u)
            v[u] = m4[tid + (k0 + u) * NV_];   // plain cached load (R9 A/B)
#pragma unroll
        for (int u = 0; u < UN_; ++u)
            r[u] = 1.0f / s[u];                // correctly-rounded reciprocal

#pragma unroll
        for (int u = 0; u < UN_; ++u) {
            f32x4 q;
#pragma unroll
            for (int kk = 0; kk < 4; ++kk) {
                float x = (s[u] != 0.0f) ? (v[u][kk] * r[u]) : 0.0f;  // safe_div
                // idx = #{bnd[j] < x}: ties DOWN (searchsorted side='left')
                float w = c[0];
#pragma unroll
                for (int j = 0; j < NC_ - 1; ++j)
                    w = (x > bnd[j]) ? c[j + 1] : w;
                q[kk] = w * s[u];
            }
            // NT store, tightly grouped (R10/R11 A/B: WC-friendly, no L3 thrash)
            __builtin_nontemporal_store(q, o4 + tid + (k0 + u) * NV_);
        }
    }
}

// ---------------------------------------------------------------------------
// Sparse override with numpy last-write-wins semantics for duplicate indices.
// Hash table (init by dequant_kernel): keys[TSIZE]=-1, vals[TSIZE]=-1.
// Pass 1: insert key, atomicMax source-index. Pass 2: winner writes.
// ---------------------------------------------------------------------------
__global__ void hash_insert(const int* __restrict__ sidx, int ns,
                            int* __restrict__ keys, int* __restrict__ vals)
{
    int i = blockIdx.x * blockDim.x + threadIdx.x;
    if (i >= ns) return;
    int key = sidx[i];
    unsigned h = ((unsigned)key * 2654435761u) >> (32 - TBITS);
    for (;;) {
        int prev = atomicCAS(&keys[h], -1, key);
        if (prev == -1 || prev == key) {
            atomicMax(&vals[h], i);   // last occurrence (max i) wins
            return;
        }
        h = (h + 1) & (TSIZE - 1);
    }
}

__global__ void hash_scatter(const int* __restrict__ sidx,
                             const float* __restrict__ sw, int ns,
                             const int* __restrict__ keys,
                             const int* __restrict__ vals,
                             float* __restrict__ out)
{
    int i = blockIdx.x * blockDim.x + threadIdx.x;
    if (i >= ns) return;
    int key = sidx[i];
    unsigned h = ((unsigned)key * 2654435761u) >> (32 - TBITS);
    for (;;) {
        if (keys[h] == key) {
            if (vals[h] == i) out[key] = sw[i];
            return;
        }
        h = (h + 1) & (TSIZE - 1);
    }
}

// Fallback if workspace is unexpectedly tiny: sequential = last-write-wins.
__global__ void serial_scatter(const int* __restrict__ sidx,
                               const float* __restrict__ sw, int ns,
                               float* __restrict__ out)
{
    if (blockIdx.x == 0 && threadIdx.x == 0) {
        for (int i = 0; i < ns; ++i) out[sidx[i]] = sw[i];
    }
}

extern "C" void kernel_launch(void* const* d_in, const int* in_sizes, int n_in,
                              void* d_out, int out_size, void* d_ws, size_t ws_size,
                              hipStream_t stream)
{
    const float* master    = (const float*)d_in[0];
    const float* centroids = (const float*)d_in[1];
    const float* scale     = (const float*)d_in[2];
    const float* sweight   = (const float*)d_in[3];
    const int*   sidx      = (const int*)d_in[4];
    float*       out       = (float*)d_out;
    const int    ns        = in_sizes[4];

    const size_t table_bytes = (size_t)TWORDS * sizeof(int);
    if (ws_size >= table_bytes) {
        int* keys = (int*)d_ws;
        int* vals = keys + TSIZE;
        // dequant also initializes the hash table (saves a fill dispatch)
        dequant_kernel<<<GRID_, BLK_, 0, stream>>>(master, centroids, scale,
                                                   out, keys);
        int blocks = (ns + 255) / 256;
        hash_insert<<<blocks, 256, 0, stream>>>(sidx, ns, keys, vals);
        hash_scatter<<<blocks, 256, 0, stream>>>(sidx, sweight, ns, keys, vals, out);
    } else {
        dequant_kernel<<<GRID_, BLK_, 0, stream>>>(master, centroids, scale,
                                                   out, (int*)d_ws);
        serial_scatter<<<1, 1, 0, stream>>>(sidx, sweight, ns, out);
    }
}

// Round 15
// 119.814 us; speedup vs baseline: 6.1941x; 1.0261x over previous
//
#include <hip/hip_runtime.h>

// Problem constants (from reference)
#define R_     4096
#define C_     16384
#define B_     32
#define NB_    (C_ / B_)     // 512
#define NC_    16
#define TOTAL  (R_ * C_)     // 67108864
#define TBITS  17
#define TSIZE  (1 << TBITS)  // 131072 hash slots (load factor 0.5)
#define TWORDS (TSIZE * 2)   // 262144 ints = 1 MB (keys + vals)

#define GRID_  16384
#define BLK_   256
#define NV_    (GRID_ * BLK_)                  // 4194304 threads
#define ITERS_ (TOTAL / 4 / NV_)               // 4 float4 per thread
#define UN_    2                               // batch depth (R9 champion)
static_assert(NV_ * ITERS_ * 4 == TOTAL, "grid must tile exactly");
static_assert(ITERS_ % UN_ == 0, "unroll divides iters");
static_assert(NV_ >= TWORDS, "one store per thread covers table init");

typedef float f32x4 __attribute__((ext_vector_type(4)));

// Force a wave-uniform float into an SGPR (keeps c[16]+bnd[15] out of VGPRs).
__device__ __forceinline__ float rfl(float x) {
    return __int_as_float(__builtin_amdgcn_readfirstlane(__float_as_int(x)));
}

// ---------------------------------------------------------------------------
// Main dequant kernel — R9 champion structure, R14 micro-tweaks kept.
//   w = centroids[searchsorted(boundaries, x)] * s,  ties DOWN (side='left')
//   x = fl32( e * fl32(1/s) )   <- matches XLA's div->mul(1/s) rewrite
// VERIFIED BITWISE (round 5, absmax 0.0). Frozen numerics:
//  - r = fl32(1/s): plain f32 IEEE divide (fast-math proven OFF in R1/R3)
//  - boundaries (c[j+1]+c[j])*0.5f ; strict '>' chain; final w*s single mul.
//
// A/B ledger (total µs): simple lane-interleaved {plain loads, NT stores}
//   130.9 (R9, grid 2048) -> 128.5 (R13, 4096) -> 122.9 (R14, 8192 +
//   scale-first)  <  nt-loads 132.4  <  nt+nt 133.6  <  plain-stores 148
//   (L3 thrash)  <  sw-pipeline 163 (WC broken)  <  per-lane-contig 742.
// R15: grid 16384 (ITERS 4) — continue the monotone grid-scaling trend
// (finer drain quanta + finer channel interleave). Last same-structure point.
// ---------------------------------------------------------------------------
__global__ __launch_bounds__(BLK_, 8) void dequant_kernel(
    const float* __restrict__ master,
    const float* __restrict__ centroids,
    const float* __restrict__ scale,
    float* __restrict__ out,
    int* __restrict__ table)
{
    // Fold the 1 MB hash-table init into this kernel (one store for the
    // first TWORDS threads) — removes a separate fill dispatch.
    const int tid = blockIdx.x * BLK_ + threadIdx.x;
    if (tid < TWORDS) __builtin_nontemporal_store(-1, table + tid);

    float c[NC_];
    float bnd[NC_ - 1];
#pragma unroll
    for (int j = 0; j < NC_; ++j) c[j] = rfl(centroids[j]);
#pragma unroll
    for (int j = 0; j < NC_ - 1; ++j)
        bnd[j] = rfl((c[j + 1] + c[j]) * 0.5f);  // f32 add, *0.5 exact; SGPR

    const f32x4* m4 = reinterpret_cast<const f32x4*>(master);
    f32x4*       o4 = reinterpret_cast<f32x4*>(out);

    for (int k0 = 0; k0 < ITERS_; k0 += UN_) {
        f32x4 v[UN_];
        float s[UN_];
        float r[UN_];

        // Scale loads FIRST: r=1/s depends only on s; div overlaps v-latency.
#pragma unroll
        for (int u = 0; u < UN_; ++u)
            s[u] = scale[(tid + (k0 + u) * NV_) >> 3];
#pragma unroll
        for (int u = 0; u < UN_; ++u)
            v[u] = m4[tid + (k0 + u) * NV_];   // plain cached load (R9 A/B)
#pragma unroll
        for (int u = 0; u < UN_; ++u)
            r[u] = 1.0f / s[u];                // correctly-rounded reciprocal

#pragma unroll
        for (int u = 0; u < UN_; ++u) {
            f32x4 q;
#pragma unroll
            for (int kk = 0; kk < 4; ++kk) {
                float x = (s[u] != 0.0f) ? (v[u][kk] * r[u]) : 0.0f;  // safe_div
                // idx = #{bnd[j] < x}: ties DOWN (searchsorted side='left')
                float w = c[0];
#pragma unroll
                for (int j = 0; j < NC_ - 1; ++j)
                    w = (x > bnd[j]) ? c[j + 1] : w;
                q[kk] = w * s[u];
            }
            // NT store, tightly grouped (R10/R11 A/B: WC-friendly, no L3 thrash)
            __builtin_nontemporal_store(q, o4 + tid + (k0 + u) * NV_);
        }
    }
}

// ---------------------------------------------------------------------------
// Sparse override with numpy last-write-wins semantics for duplicate indices.
// Hash table (init by dequant_kernel): keys[TSIZE]=-1, vals[TSIZE]=-1.
// Pass 1: insert key, atomicMax source-index. Pass 2: winner writes.
// ---------------------------------------------------------------------------
__global__ void hash_insert(const int* __restrict__ sidx, int ns,
                            int* __restrict__ keys, int* __restrict__ vals)
{
    int i = blockIdx.x * blockDim.x + threadIdx.x;
    if (i >= ns) return;
    int key = sidx[i];
    unsigned h = ((unsigned)key * 2654435761u) >> (32 - TBITS);
    for (;;) {
        int prev = atomicCAS(&keys[h], -1, key);
        if (prev == -1 || prev == key) {
            atomicMax(&vals[h], i);   // last occurrence (max i) wins
            return;
        }
        h = (h + 1) & (TSIZE - 1);
    }
}

__global__ void hash_scatter(const int* __restrict__ sidx,
                             const float* __restrict__ sw, int ns,
                             const int* __restrict__ keys,
                             const int* __restrict__ vals,
                             float* __restrict__ out)
{
    int i = blockIdx.x * blockDim.x + threadIdx.x;
    if (i >= ns) return;
    int key = sidx[i];
    unsigned h = ((unsigned)key * 2654435761u) >> (32 - TBITS);
    for (;;) {
        if (keys[h] == key) {
            if (vals[h] == i) out[key] = sw[i];
            return;
        }
        h = (h + 1) & (TSIZE - 1);
    }
}

// Fallback if workspace is unexpectedly tiny: sequential = last-write-wins.
__global__ void serial_scatter(const int* __restrict__ sidx,
                               const float* __restrict__ sw, int ns,
                               float* __restrict__ out)
{
    if (blockIdx.x == 0 && threadIdx.x == 0) {
        for (int i = 0; i < ns; ++i) out[sidx[i]] = sw[i];
    }
}

extern "C" void kernel_launch(void* const* d_in, const int* in_sizes, int n_in,
                              void* d_out, int out_size, void* d_ws, size_t ws_size,
                              hipStream_t stream)
{
    const float* master    = (const float*)d_in[0];
    const float* centroids = (const float*)d_in[1];
    const float* scale     = (const float*)d_in[2];
    const float* sweight   = (const float*)d_in[3];
    const int*   sidx      = (const int*)d_in[4];
    float*       out       = (float*)d_out;
    const int    ns        = in_sizes[4];

    const size_t table_bytes = (size_t)TWORDS * sizeof(int);
    if (ws_size >= table_bytes) {
        int* keys = (int*)d_ws;
        int* vals = keys + TSIZE;
        // dequant also initializes the hash table (saves a fill dispatch)
        dequant_kernel<<<GRID_, BLK_, 0, stream>>>(master, centroids, scale,
                                                   out, keys);
        int blocks = (ns + 255) / 256;
        hash_insert<<<blocks, 256, 0, stream>>>(sidx, ns, keys, vals);
        hash_scatter<<<blocks, 256, 0, stream>>>(sidx, sweight, ns, keys, vals, out);
    } else {
        dequant_kernel<<<GRID_, BLK_, 0, stream>>>(master, centroids, scale,
                                                   out, (int*)d_ws);
        serial_scatter<<<1, 1, 0, stream>>>(sidx, sweight, ns, out);
    }
}

// Round 16
// 118.966 us; speedup vs baseline: 6.2382x; 1.0071x over previous
//
#include <hip/hip_runtime.h>

// Problem constants (from reference)
#define R_     4096
#define C_     16384
#define B_     32
#define NB_    (C_ / B_)     // 512
#define NC_    16
#define TOTAL  (R_ * C_)     // 67108864
#define TBITS  17
#define TSIZE  (1 << TBITS)  // 131072 hash slots (load factor 0.5)
#define TWORDS (TSIZE * 2)   // 262144 ints = 1 MB (keys + vals)

#define GRID_  32768
#define BLK_   256
#define NV_    (GRID_ * BLK_)                  // 8388608 threads
#define ITERS_ (TOTAL / 4 / NV_)               // 2 float4 per thread
#define UN_    2                               // = ITERS_: single group, no loop
static_assert(NV_ * ITERS_ * 4 == TOTAL, "grid must tile exactly");
static_assert(ITERS_ == UN_, "single straight-line group");
static_assert(NV_ >= TWORDS, "one store per thread covers table init");

typedef float f32x4 __attribute__((ext_vector_type(4)));

// Force a wave-uniform float into an SGPR (keeps c[16]+bnd[15] out of VGPRs).
__device__ __forceinline__ float rfl(float x) {
    return __int_as_float(__builtin_amdgcn_readfirstlane(__float_as_int(x)));
}

// ---------------------------------------------------------------------------
// Main dequant kernel — champion structure, loop fully eliminated.
//   w = centroids[searchsorted(boundaries, x)] * s,  ties DOWN (side='left')
//   x = fl32( e * fl32(1/s) )   <- matches XLA's div->mul(1/s) rewrite
// VERIFIED BITWISE (round 5, absmax 0.0). Frozen numerics:
//  - r = fl32(1/s): plain f32 IEEE divide (fast-math proven OFF in R1/R3)
//  - boundaries (c[j+1]+c[j])*0.5f ; strict '>' chain; final w*s single mul.
//
// A/B ledger (total µs): simple lane-interleaved {plain loads, NT stores}
//   130.9 (R9, grid 2048) -> 128.5 (4096) -> 122.9 (8192 + scale-first)
//   -> 119.8 (16384)  <  nt-loads 132.4  <  nt+nt 133.6  <  plain-stores
//   148 (L3 thrash)  <  sw-pipeline 163 (WC broken)  <  per-lane-contig 742.
// R16: grid 32768 -> ITERS=2 = one straight-line UN=2 group (no loop):
// endpoint of the work-quantum-shrinking trend.
// ---------------------------------------------------------------------------
__global__ __launch_bounds__(BLK_, 8) void dequant_kernel(
    const float* __restrict__ master,
    const float* __restrict__ centroids,
    const float* __restrict__ scale,
    float* __restrict__ out,
    int* __restrict__ table)
{
    // Fold the 1 MB hash-table init into this kernel (one store for the
    // first TWORDS threads) — removes a separate fill dispatch.
    const int tid = blockIdx.x * BLK_ + threadIdx.x;
    if (tid < TWORDS) __builtin_nontemporal_store(-1, table + tid);

    float c[NC_];
    float bnd[NC_ - 1];
#pragma unroll
    for (int j = 0; j < NC_; ++j) c[j] = rfl(centroids[j]);
#pragma unroll
    for (int j = 0; j < NC_ - 1; ++j)
        bnd[j] = rfl((c[j + 1] + c[j]) * 0.5f);  // f32 add, *0.5 exact; SGPR

    const f32x4* m4 = reinterpret_cast<const f32x4*>(master);
    f32x4*       o4 = reinterpret_cast<f32x4*>(out);

    f32x4 v[UN_];
    float s[UN_];
    float r[UN_];

    // Scale loads FIRST: r=1/s depends only on s; div overlaps v-latency.
#pragma unroll
    for (int u = 0; u < UN_; ++u)
        s[u] = scale[(tid + u * NV_) >> 3];
#pragma unroll
    for (int u = 0; u < UN_; ++u)
        v[u] = m4[tid + u * NV_];          // plain cached load (R9 A/B)
#pragma unroll
    for (int u = 0; u < UN_; ++u)
        r[u] = 1.0f / s[u];                // correctly-rounded reciprocal

#pragma unroll
    for (int u = 0; u < UN_; ++u) {
        f32x4 q;
#pragma unroll
        for (int kk = 0; kk < 4; ++kk) {
            float x = (s[u] != 0.0f) ? (v[u][kk] * r[u]) : 0.0f;  // safe_div
            // idx = #{bnd[j] < x}: ties DOWN (searchsorted side='left')
            float w = c[0];
#pragma unroll
            for (int j = 0; j < NC_ - 1; ++j)
                w = (x > bnd[j]) ? c[j + 1] : w;
            q[kk] = w * s[u];
        }
        // NT store, tightly grouped (R10/R11 A/B: WC-friendly, no L3 thrash)
        __builtin_nontemporal_store(q, o4 + tid + u * NV_);
    }
}

// ---------------------------------------------------------------------------
// Sparse override with numpy last-write-wins semantics for duplicate indices.
// Hash table (init by dequant_kernel): keys[TSIZE]=-1, vals[TSIZE]=-1.
// Pass 1: insert key, atomicMax source-index. Pass 2: winner writes.
// ---------------------------------------------------------------------------
__global__ void hash_insert(const int* __restrict__ sidx, int ns,
                            int* __restrict__ keys, int* __restrict__ vals)
{
    int i = blockIdx.x * blockDim.x + threadIdx.x;
    if (i >= ns) return;
    int key = sidx[i];
    unsigned h = ((unsigned)key * 2654435761u) >> (32 - TBITS);
    for (;;) {
        int prev = atomicCAS(&keys[h], -1, key);
        if (prev == -1 || prev == key) {
            atomicMax(&vals[h], i);   // last occurrence (max i) wins
            return;
        }
        h = (h + 1) & (TSIZE - 1);
    }
}

__global__ void hash_scatter(const int* __restrict__ sidx,
                             const float* __restrict__ sw, int ns,
                             const int* __restrict__ keys,
                             const int* __restrict__ vals,
                             float* __restrict__ out)
{
    int i = blockIdx.x * blockDim.x + threadIdx.x;
    if (i >= ns) return;
    int key = sidx[i];
    unsigned h = ((unsigned)key * 2654435761u) >> (32 - TBITS);
    for (;;) {
        if (keys[h] == key) {
            if (vals[h] == i) out[key] = sw[i];
            return;
        }
        h = (h + 1) & (TSIZE - 1);
    }
}

// Fallback if workspace is unexpectedly tiny: sequential = last-write-wins.
__global__ void serial_scatter(const int* __restrict__ sidx,
                               const float* __restrict__ sw, int ns,
                               float* __restrict__ out)
{
    if (blockIdx.x == 0 && threadIdx.x == 0) {
        for (int i = 0; i < ns; ++i) out[sidx[i]] = sw[i];
    }
}

extern "C" void kernel_launch(void* const* d_in, const int* in_sizes, int n_in,
                              void* d_out, int out_size, void* d_ws, size_t ws_size,
                              hipStream_t stream)
{
    const float* master    = (const float*)d_in[0];
    const float* centroids = (const float*)d_in[1];
    const float* scale     = (const float*)d_in[2];
    const float* sweight   = (const float*)d_in[3];
    const int*   sidx      = (const int*)d_in[4];
    float*       out       = (float*)d_out;
    const int    ns        = in_sizes[4];

    const size_t table_bytes = (size_t)TWORDS * sizeof(int);
    if (ws_size >= table_bytes) {
        int* keys = (int*)d_ws;
        int* vals = keys + TSIZE;
        // dequant also initializes the hash table (saves a fill dispatch)
        dequant_kernel<<<GRID_, BLK_, 0, stream>>>(master, centroids, scale,
                                                   out, keys);
        int blocks = (ns + 255) / 256;
        hash_insert<<<blocks, 256, 0, stream>>>(sidx, ns, keys, vals);
        hash_scatter<<<blocks, 256, 0, stream>>>(sidx, sweight, ns, keys, vals, out);
    } else {
        dequant_kernel<<<GRID_, BLK_, 0, stream>>>(master, centroids, scale,
                                                   out, (int*)d_ws);
        serial_scatter<<<1, 1, 0, stream>>>(sidx, sweight, ns, out);
    }
}